// Round 1
// baseline (1370.387 us; speedup 1.0000x reference)
//
#include <hip/hip_runtime.h>
#include <hip/hip_bf16.h>
#include <stdint.h>

#define NT 4096   // tokens
#define DD 1024   // model dim
#define HH 4096   // hidden dim
#define NEXP 8    // experts
// TOP_K = 2 handled in gating

typedef __attribute__((ext_vector_type(8))) short bf16x8;
typedef __attribute__((ext_vector_type(4))) float f32x4;

__device__ inline ushort f2b(float f) {
  union { float f; uint32_t u; } v; v.f = f;
  uint32_t u = v.u;
  return (ushort)((u + 0x7fffu + ((u >> 16) & 1u)) >> 16);  // RNE
}

// ---------------- gating: softmax(x@Wg+bg), top-2, dense weights [NT, NEXP] --
__global__ __launch_bounds__(256) void gating_kernel(
    const float* __restrict__ x, const float* __restrict__ Wg,
    const float* __restrict__ bg, float* __restrict__ wgt) {
  int gw = (blockIdx.x * 256 + threadIdx.x) >> 6;  // one wave per token
  int lane = threadIdx.x & 63;
  if (gw >= NT) return;
  const float* xr = x + (size_t)gw * DD;
  float acc[NEXP];
#pragma unroll
  for (int e = 0; e < NEXP; e++) acc[e] = 0.f;
  for (int d = lane; d < DD; d += 64) {
    float xv = xr[d];
    const float* wr = Wg + (size_t)d * NEXP;
#pragma unroll
    for (int e = 0; e < NEXP; e++) acc[e] += xv * wr[e];
  }
#pragma unroll
  for (int off = 32; off > 0; off >>= 1) {
#pragma unroll
    for (int e = 0; e < NEXP; e++) acc[e] += __shfl_xor(acc[e], off, 64);
  }
  float l[NEXP], m = -1e30f;
#pragma unroll
  for (int e = 0; e < NEXP; e++) { l[e] = acc[e] + bg[e]; m = fmaxf(m, l[e]); }
  float s = 0.f;
#pragma unroll
  for (int e = 0; e < NEXP; e++) { l[e] = expf(l[e] - m); s += l[e]; }
  float inv = 1.f / s;
  // top-2, ties -> lower index (strict >) to match jax.lax.top_k
  float v1 = -1.f, v2 = -1.f; int i1 = -1, i2 = -1;
#pragma unroll
  for (int e = 0; e < NEXP; e++) {
    float p = l[e] * inv;
    if (p > v1) { v2 = v1; i2 = i1; v1 = p; i1 = e; }
    else if (p > v2) { v2 = p; i2 = e; }
  }
  if (lane < NEXP) {
    float w = (lane == i1) ? v1 : ((lane == i2) ? v2 : 0.f);
    wgt[(size_t)gw * NEXP + lane] = w;
  }
}

// ---------------- fp32 -> bf16 elementwise (x) -------------------------------
__global__ __launch_bounds__(256) void cvt_x_kernel(
    const float* __restrict__ in, ushort* __restrict__ out, int n) {
  int i = (blockIdx.x * 256 + threadIdx.x) * 4;
  if (i >= n) return;
  float4 v = *(const float4*)(in + i);
  ushort4 o; o.x = f2b(v.x); o.y = f2b(v.y); o.z = f2b(v.z); o.w = f2b(v.w);
  *(ushort4*)(out + i) = o;
}

// ---------------- fp32 [R][C] -> bf16 transposed [C][R] ----------------------
__global__ __launch_bounds__(256) void transpose_cvt_kernel(
    const float* __restrict__ in, ushort* __restrict__ out, int R, int C) {
  __shared__ float t[32][33];
  int c0 = blockIdx.x * 32, r0 = blockIdx.y * 32;
  int tx = threadIdx.x & 31, ty = threadIdx.x >> 5;  // 32 x 8
#pragma unroll
  for (int i = 0; i < 4; i++) {
    int r = ty + i * 8;
    t[r][tx] = in[(size_t)(r0 + r) * C + c0 + tx];
  }
  __syncthreads();
#pragma unroll
  for (int i = 0; i < 4; i++) {
    int cc = ty + i * 8;
    out[(size_t)(c0 + cc) * R + r0 + tx] = f2b(t[tx][cc]);
  }
}

// ---------------- GEMM: C[M][N] = A[M][K] @ Bt[N][K]^T -----------------------
// MODE 1: hb[m][n] = bf16(relu(acc + bias[n]))
// MODE 2: out[m][n] += wgt[m*8+e] * (acc + bias[n])   (skip rows w/ weight 0)
template <int MODE>
__global__ __launch_bounds__(256, 2) void gemm_bt_kernel(
    const ushort* __restrict__ A, const ushort* __restrict__ Bt,
    const float* __restrict__ bias, void* __restrict__ Cout,
    const float* __restrict__ wgt, int M, int Nn, int K, int expert) {
  const int BM = 128, BN = 128, BK = 32;
  __shared__ __align__(16) ushort As[BM * BK];
  __shared__ __align__(16) ushort Bs[BN * BK];
  int tid = threadIdx.x;
  int m0 = blockIdx.y * BM;
  int n0 = blockIdx.x * BN;
  int wv = tid >> 6, lane = tid & 63;
  int wr = (wv >> 1) * 64;       // wave row offset in tile
  int wc = (wv & 1) * 64;        // wave col offset
  int lr = lane & 15;
  int kq = (lane >> 4) * 8;

  f32x4 acc[4][4];
#pragma unroll
  for (int i = 0; i < 4; i++)
#pragma unroll
    for (int j = 0; j < 4; j++) acc[i][j] = (f32x4)(0.f);

  int r0 = tid >> 2;             // staging row (0..63), 2 passes of 64 rows
  int c0 = (tid & 3) * 8;        // staging col in bf16 elems

  for (int k0 = 0; k0 < K; k0 += BK) {
    uint4 av0 = *(const uint4*)(A + (size_t)(m0 + r0) * K + k0 + c0);
    uint4 av1 = *(const uint4*)(A + (size_t)(m0 + 64 + r0) * K + k0 + c0);
    uint4 bv0 = *(const uint4*)(Bt + (size_t)(n0 + r0) * K + k0 + c0);
    uint4 bv1 = *(const uint4*)(Bt + (size_t)(n0 + 64 + r0) * K + k0 + c0);
    __syncthreads();  // previous iter's frag reads done before overwrite
    *(uint4*)&As[r0 * BK + c0] = av0;
    *(uint4*)&As[(64 + r0) * BK + c0] = av1;
    *(uint4*)&Bs[r0 * BK + c0] = bv0;
    *(uint4*)&Bs[(64 + r0) * BK + c0] = bv1;
    __syncthreads();
    bf16x8 af[4], bfr[4];
#pragma unroll
    for (int i = 0; i < 4; i++)
      af[i] = *(const bf16x8*)&As[(wr + i * 16 + lr) * BK + kq];
#pragma unroll
    for (int j = 0; j < 4; j++)
      bfr[j] = *(const bf16x8*)&Bs[(wc + j * 16 + lr) * BK + kq];
#pragma unroll
    for (int i = 0; i < 4; i++)
#pragma unroll
      for (int j = 0; j < 4; j++)
        acc[i][j] = __builtin_amdgcn_mfma_f32_16x16x32_bf16(af[i], bfr[j],
                                                            acc[i][j], 0, 0, 0);
  }

  // epilogue: C/D layout col = lane&15, row = (lane>>4)*4 + reg
  int rq = (lane >> 4) * 4;
  if (MODE == 1) {
    ushort* Cb = (ushort*)Cout;
#pragma unroll
    for (int i = 0; i < 4; i++) {
#pragma unroll
      for (int r = 0; r < 4; r++) {
        int row = m0 + wr + i * 16 + rq + r;
#pragma unroll
        for (int j = 0; j < 4; j++) {
          int col = n0 + wc + j * 16 + lr;
          float v = acc[i][j][r] + bias[col];
          v = fmaxf(v, 0.f);
          Cb[(size_t)row * Nn + col] = f2b(v);
        }
      }
    }
  } else {
    float* Co = (float*)Cout;
#pragma unroll
    for (int i = 0; i < 4; i++) {
#pragma unroll
      for (int r = 0; r < 4; r++) {
        int row = m0 + wr + i * 16 + rq + r;
        float w = wgt[(size_t)row * NEXP + expert];
        if (w != 0.f) {
#pragma unroll
          for (int j = 0; j < 4; j++) {
            int col = n0 + wc + j * 16 + lr;
            Co[(size_t)row * Nn + col] += w * (acc[i][j][r] + bias[col]);
          }
        }
      }
    }
  }
}

extern "C" void kernel_launch(void* const* d_in, const int* in_sizes, int n_in,
                              void* d_out, int out_size, void* d_ws,
                              size_t ws_size, hipStream_t stream) {
  const float* x  = (const float*)d_in[0];
  const float* Wg = (const float*)d_in[1];
  const float* bg = (const float*)d_in[2];
  const float* W1 = (const float*)d_in[3];
  const float* b1 = (const float*)d_in[4];
  const float* W2 = (const float*)d_in[5];
  const float* b2 = (const float*)d_in[6];
  float* out = (float*)d_out;

  char* ws = (char*)d_ws;
  ushort* xb  = (ushort*)ws;                         // 8 MB: x bf16 [NT][DD]
  ushort* hb  = (ushort*)(ws + (8u << 20));          // 32 MB: h bf16 [NT][HH]
  ushort* w1t = (ushort*)(ws + (42u << 20));         // 8 MB: W1_e^T [HH][DD]
  ushort* w2t = (ushort*)(ws + (51u << 20));         // 8 MB: W2_e^T [DD][HH]
  float*  wgt = (float*)(ws + (60u << 20));          // 128 KB: weights [NT][8]

  hipMemsetAsync(d_out, 0, (size_t)out_size * sizeof(float), stream);

  gating_kernel<<<NT / 4, 256, 0, stream>>>(x, Wg, bg, wgt);
  cvt_x_kernel<<<(NT * DD / 4 + 255) / 256, 256, 0, stream>>>(x, xb, NT * DD);

  for (int e = 0; e < NEXP; e++) {
    // W1_e [DD][HH] -> w1t [HH][DD]
    transpose_cvt_kernel<<<dim3(HH / 32, DD / 32), 256, 0, stream>>>(
        W1 + (size_t)e * DD * HH, w1t, DD, HH);
    // h = relu(x @ W1_e + b1_e)
    gemm_bt_kernel<1><<<dim3(HH / 128, NT / 128), 256, 0, stream>>>(
        xb, w1t, b1 + (size_t)e * HH, hb, nullptr, NT, HH, DD, e);
    // W2_e [HH][DD] -> w2t [DD][HH]
    transpose_cvt_kernel<<<dim3(DD / 32, HH / 32), 256, 0, stream>>>(
        W2 + (size_t)e * HH * DD, w2t, HH, DD);
    // out += w[:,e] * (h @ W2_e + b2_e)
    gemm_bt_kernel<2><<<dim3(DD / 128, NT / 128), 256, 0, stream>>>(
        hb, w2t, b2 + (size_t)e * DD, out, wgt, NT, DD, HH, e);
  }
}

// Round 2
// 797.158 us; speedup vs baseline: 1.7191x; 1.7191x over previous
//
#include <hip/hip_runtime.h>
#include <hip/hip_bf16.h>
#include <stdint.h>

#define NT 4096   // tokens
#define DD 1024   // model dim
#define HH 4096   // hidden dim
#define NEXP 8    // experts
// TOP_K = 2

typedef __attribute__((ext_vector_type(8))) short bf16x8;
typedef __attribute__((ext_vector_type(4))) float f32x4;

// async global->LDS, 16B per lane; LDS dest is wave-uniform base + lane*16
#define GLOAD16(g, l) __builtin_amdgcn_global_load_lds( \
    (const __attribute__((address_space(1))) void*)(g), \
    (__attribute__((address_space(3))) void*)(l), 16, 0, 0)

__device__ inline ushort f2b(float f) {
  union { float f; uint32_t u; } v; v.f = f;
  uint32_t u = v.u;
  return (ushort)((u + 0x7fffu + ((u >> 16) & 1u)) >> 16);  // RNE
}

// ---- gating: softmax(x@Wg+bg); top-2 -> dense wgt, tidx/tval, counts -------
__global__ __launch_bounds__(256) void gating_kernel(
    const float* __restrict__ x, const float* __restrict__ Wg,
    const float* __restrict__ bg, float* __restrict__ wgt,
    int* __restrict__ tidx, float* __restrict__ tval, int* __restrict__ counts) {
  int gw = (blockIdx.x * 256 + threadIdx.x) >> 6;  // one wave per token
  int lane = threadIdx.x & 63;
  if (gw >= NT) return;
  const float* xr = x + (size_t)gw * DD;
  float acc[NEXP];
#pragma unroll
  for (int e = 0; e < NEXP; e++) acc[e] = 0.f;
  for (int d = lane; d < DD; d += 64) {
    float xv = xr[d];
    const float* wr = Wg + (size_t)d * NEXP;
#pragma unroll
    for (int e = 0; e < NEXP; e++) acc[e] += xv * wr[e];
  }
#pragma unroll
  for (int off = 32; off > 0; off >>= 1) {
#pragma unroll
    for (int e = 0; e < NEXP; e++) acc[e] += __shfl_xor(acc[e], off, 64);
  }
  float l[NEXP], m = -1e30f;
#pragma unroll
  for (int e = 0; e < NEXP; e++) { l[e] = acc[e] + bg[e]; m = fmaxf(m, l[e]); }
  float s = 0.f;
#pragma unroll
  for (int e = 0; e < NEXP; e++) { l[e] = expf(l[e] - m); s += l[e]; }
  float inv = 1.f / s;
  float v1 = -1.f, v2 = -1.f; int i1 = -1, i2 = -1;
#pragma unroll
  for (int e = 0; e < NEXP; e++) {
    float p = l[e] * inv;
    if (p > v1) { v2 = v1; i2 = i1; v1 = p; i1 = e; }
    else if (p > v2) { v2 = p; i2 = e; }
  }
  if (lane < NEXP) {
    float w = (lane == i1) ? v1 : ((lane == i2) ? v2 : 0.f);
    wgt[(size_t)gw * NEXP + lane] = w;
  }
  if (lane == 0) {
    tidx[gw * 2 + 0] = i1; tval[gw * 2 + 0] = v1;
    tidx[gw * 2 + 1] = i2; tval[gw * 2 + 1] = v2;
    atomicAdd(&counts[i1], 1);
    atomicAdd(&counts[i2], 1);
  }
}

// ---- base[e] = 128-aligned prefix of counts --------------------------------
__global__ void scan_kernel(const int* __restrict__ counts, int* __restrict__ base) {
  int b = 0;
#pragma unroll
  for (int e = 0; e < NEXP; e++) { base[e] = b; b += ((counts[e] + 127) >> 7) << 7; }
}

// ---- scatter tokens into expert-grouped pair list --------------------------
__global__ __launch_bounds__(256) void scatter_kernel(
    const int* __restrict__ tidx, const float* __restrict__ tval,
    const int* __restrict__ base, int* __restrict__ cursor,
    int* __restrict__ perm, float* __restrict__ pairw) {
  int t = blockIdx.x * 256 + threadIdx.x;
  if (t >= NT) return;
#pragma unroll
  for (int k = 0; k < 2; k++) {
    int e = tidx[t * 2 + k];
    int pos = atomicAdd(&cursor[e], 1);
    int p = base[e] + pos;
    perm[p] = t;
    pairw[p] = tval[t * 2 + k];
  }
}

// ---- fp32 -> bf16 elementwise (x) ------------------------------------------
__global__ __launch_bounds__(256) void cvt_x_kernel(
    const float* __restrict__ in, ushort* __restrict__ out, int n) {
  int i = (blockIdx.x * 256 + threadIdx.x) * 4;
  if (i >= n) return;
  float4 v = *(const float4*)(in + i);
  ushort4 o; o.x = f2b(v.x); o.y = f2b(v.y); o.z = f2b(v.z); o.w = f2b(v.w);
  *(ushort4*)(out + i) = o;
}

// ---- fp32 [R][C] -> bf16 [C][R], per-expert via blockIdx.z -----------------
__global__ __launch_bounds__(256) void transpose_cvt_kernel(
    const float* __restrict__ in, ushort* __restrict__ out, int R, int C) {
  __shared__ float t[32][33];
  size_t eo = (size_t)blockIdx.z * R * C;
  in += eo; out += eo;
  int c0 = blockIdx.x * 32, r0 = blockIdx.y * 32;
  int tx = threadIdx.x & 31, ty = threadIdx.x >> 5;  // 32 x 8
#pragma unroll
  for (int i = 0; i < 4; i++) {
    int r = ty + i * 8;
    t[r][tx] = in[(size_t)(r0 + r) * C + c0 + tx];
  }
  __syncthreads();
#pragma unroll
  for (int i = 0; i < 4; i++) {
    int cc = ty + i * 8;
    out[(size_t)(c0 + cc) * R + r0 + tx] = f2b(t[tx][cc]);
  }
}

// ---- GEMM: C[M][N] = A[M][K] @ Bt[N][K]^T, global_load_lds staging ---------
// MODE 1: store bf16(relu(acc+bias)) to Cout rows (pair/token index)
// MODE 2: accumulate w*(acc+bias) into out[token] (atomic when SPARSE)
template <int MODE, bool SPARSE>
__global__ __launch_bounds__(256) void gemm_bt_kernel(
    const ushort* __restrict__ A, const ushort* __restrict__ BtAll,
    const float* __restrict__ biasAll, void* __restrict__ Cout,
    const int* __restrict__ perm, const float* __restrict__ pairw,
    const float* __restrict__ wgtDense,
    const int* __restrict__ base, const int* __restrict__ cnt,
    int Nn, int K, int eFixed) {
  const int BK = 32;
  __shared__ __align__(16) ushort As[128 * BK];
  __shared__ __align__(16) ushort Bs[128 * BK];
  int e, m0;
  if (SPARSE) {
    e = blockIdx.z;
    if ((int)blockIdx.y * 128 >= cnt[e]) return;   // expert has no rows here
    m0 = base[e] + blockIdx.y * 128;
  } else {
    e = eFixed;
    m0 = blockIdx.y * 128;
  }
  int n0 = blockIdx.x * 128;
  const ushort* Bt = SPARSE ? BtAll + (size_t)e * Nn * K : BtAll;
  const float* bias = biasAll + (size_t)e * Nn;

  int tid = threadIdx.x, wv = tid >> 6, lane = tid & 63;
  // staging geometry: wave wv stages rows [wv*32, wv*32+32) of As and Bs,
  // two 16-row x 64B chunks; lane covers row lane>>2, 16B col (lane&3)
  int sr = lane >> 2;
  int sc = (lane & 3) * 8;  // ushort col
  int ar0 = m0 + wv * 32 + sr, ar1 = ar0 + 16;
  int64_t gr0, gr1;
  if (SPARSE && MODE == 1) { gr0 = perm[ar0]; gr1 = perm[ar1]; }
  else { gr0 = ar0; gr1 = ar1; }
  const ushort* gA0 = A + gr0 * (int64_t)K + sc;
  const ushort* gA1 = A + gr1 * (int64_t)K + sc;
  const ushort* gB0 = Bt + (int64_t)(n0 + wv * 32 + sr) * K + sc;
  const ushort* gB1 = gB0 + (int64_t)16 * K;
  ushort* lA0 = &As[(wv * 32) * BK];
  ushort* lA1 = &As[(wv * 32 + 16) * BK];
  ushort* lB0 = &Bs[(wv * 32) * BK];
  ushort* lB1 = &Bs[(wv * 32 + 16) * BK];

  int wr = (wv >> 1) * 64;   // wave's 64x64 quadrant
  int wc = (wv & 1) * 64;
  int lr = lane & 15;
  int kq = (lane >> 4) * 8;

  f32x4 acc[4][4];
#pragma unroll
  for (int i = 0; i < 4; i++)
#pragma unroll
    for (int j = 0; j < 4; j++) acc[i][j] = (f32x4)(0.f);

  for (int k0 = 0; k0 < K; k0 += BK) {
    __syncthreads();               // prior frag reads done before DMA lands
    GLOAD16(gA0 + k0, lA0);
    GLOAD16(gA1 + k0, lA1);
    GLOAD16(gB0 + k0, lB0);
    GLOAD16(gB1 + k0, lB1);
    __syncthreads();               // drains vmcnt -> tiles visible
    bf16x8 af[4], bfr[4];
#pragma unroll
    for (int i = 0; i < 4; i++)
      af[i] = *(const bf16x8*)&As[(wr + i * 16 + lr) * BK + kq];
#pragma unroll
    for (int j = 0; j < 4; j++)
      bfr[j] = *(const bf16x8*)&Bs[(wc + j * 16 + lr) * BK + kq];
#pragma unroll
    for (int i = 0; i < 4; i++)
#pragma unroll
      for (int j = 0; j < 4; j++)
        acc[i][j] = __builtin_amdgcn_mfma_f32_16x16x32_bf16(af[i], bfr[j],
                                                            acc[i][j], 0, 0, 0);
  }

  // epilogue: C/D layout col = lane&15, row = (lane>>4)*4 + reg
  int rq = (lane >> 4) * 4;
  if (MODE == 1) {
    ushort* Cb = (ushort*)Cout;
#pragma unroll
    for (int i = 0; i < 4; i++) {
#pragma unroll
      for (int r = 0; r < 4; r++) {
        int row = m0 + wr + i * 16 + rq + r;
#pragma unroll
        for (int j = 0; j < 4; j++) {
          int col = n0 + wc + j * 16 + lr;
          float v = acc[i][j][r] + bias[col];
          Cb[(size_t)row * Nn + col] = f2b(fmaxf(v, 0.f));
        }
      }
    }
  } else {
    float* Co = (float*)Cout;
#pragma unroll
    for (int i = 0; i < 4; i++) {
#pragma unroll
      for (int r = 0; r < 4; r++) {
        int row = m0 + wr + i * 16 + rq + r;
        if (SPARSE) {
          float w = pairw[row];
          if (w != 0.f) {
            int t = perm[row];
#pragma unroll
            for (int j = 0; j < 4; j++) {
              int col = n0 + wc + j * 16 + lr;
              atomicAdd(&Co[(size_t)t * DD + col], w * (acc[i][j][r] + bias[col]));
            }
          }
        } else {
          float w = wgtDense[(size_t)row * NEXP + e];
          if (w != 0.f) {
#pragma unroll
            for (int j = 0; j < 4; j++) {
              int col = n0 + wc + j * 16 + lr;
              Co[(size_t)row * Nn + col] += w * (acc[i][j][r] + bias[col]);
            }
          }
        }
      }
    }
  }
}

extern "C" void kernel_launch(void* const* d_in, const int* in_sizes, int n_in,
                              void* d_out, int out_size, void* d_ws,
                              size_t ws_size, hipStream_t stream) {
  const float* x  = (const float*)d_in[0];
  const float* Wg = (const float*)d_in[1];
  const float* bg = (const float*)d_in[2];
  const float* W1 = (const float*)d_in[3];
  const float* b1 = (const float*)d_in[4];
  const float* W2 = (const float*)d_in[5];
  const float* b2 = (const float*)d_in[6];
  float* out = (float*)d_out;
  char* ws = (char*)d_ws;

  hipMemsetAsync(d_out, 0, (size_t)out_size * sizeof(float), stream);

  // ---- Tier A: sparse pair-grouped path. Needs ~218.4 MB workspace. ----
  const size_t XB_SZ   = (size_t)NT * DD * 2;          //   8 MiB
  const size_t WT_SZ   = (size_t)NEXP * DD * HH * 2;   //  64 MiB each
  const size_t HB_ROWS = 9216;                         // 8192 pairs + pad
  const size_t HB_SZ   = HB_ROWS * HH * 2;             //  72 MiB
  const size_t W1T_OFF = XB_SZ;
  const size_t W2T_OFF = W1T_OFF + WT_SZ;
  const size_t HB_OFF  = W2T_OFF + WT_SZ;
  const size_t SM_OFF  = HB_OFF + HB_SZ;               // 218,103,808
  const size_t TIER_A_NEED = SM_OFF + 275456;

  if (ws_size >= TIER_A_NEED) {
    ushort* xb   = (ushort*)ws;
    ushort* w1t  = (ushort*)(ws + W1T_OFF);
    ushort* w2t  = (ushort*)(ws + W2T_OFF);
    ushort* hbuf = (ushort*)(ws + HB_OFF);
    char* sm = ws + SM_OFF;
    int*   counts = (int*)(sm + 0);
    int*   cursor = (int*)(sm + 128);
    int*   base   = (int*)(sm + 256);
    int*   tidx   = (int*)(sm + 1024);
    float* tval   = (float*)(sm + 1024 + 32768);
    int*   perm   = (int*)(sm + 68608);
    float* pairw  = (float*)(sm + 105472);
    float* wgt    = (float*)(sm + 143360);  // dense (unused by sparse GEMM)

    hipMemsetAsync(sm, 0, 142336, stream);  // counts/cursor/base/perm/pairw

    gating_kernel<<<NT / 4, 256, 0, stream>>>(x, Wg, bg, wgt, tidx, tval, counts);
    cvt_x_kernel<<<(NT * DD / 4 + 255) / 256, 256, 0, stream>>>(x, xb, NT * DD);
    scan_kernel<<<1, 1, 0, stream>>>(counts, base);
    scatter_kernel<<<NT / 256, 256, 0, stream>>>(tidx, tval, base, cursor, perm, pairw);

    // all-expert weight transposes (bf16)
    transpose_cvt_kernel<<<dim3(HH / 32, DD / 32, NEXP), 256, 0, stream>>>(W1, w1t, DD, HH);
    transpose_cvt_kernel<<<dim3(DD / 32, HH / 32, NEXP), 256, 0, stream>>>(W2, w2t, HH, DD);

    // h[p] = relu(x[perm[p]] @ W1_e + b1_e)   (merged over experts)
    gemm_bt_kernel<1, true><<<dim3(HH / 128, NT / 128, NEXP), 256, 0, stream>>>(
        xb, w1t, b1, hbuf, perm, pairw, nullptr, base, counts, HH, DD, 0);
    // out[perm[p]] += pairw[p] * (h[p] @ W2_e + b2_e)
    gemm_bt_kernel<2, true><<<dim3(DD / 128, NT / 128, NEXP), 256, 0, stream>>>(
        hbuf, w2t, b2, out, perm, pairw, nullptr, base, counts, DD, HH, 0);
    return;
  }

  // ---- Tier B: dense per-expert path (round-1 footprint, new GEMM) ----
  ushort* xb  = (ushort*)ws;                         // 8 MiB
  ushort* hb  = (ushort*)(ws + (8u << 20));          // 32 MiB
  ushort* w1t = (ushort*)(ws + (42u << 20));         // 8 MiB
  ushort* w2t = (ushort*)(ws + (51u << 20));         // 8 MiB
  char* sm2 = ws + (59u << 20);                      // gap inside footprint
  int*   tidx   = (int*)(sm2);
  float* tval   = (float*)(sm2 + 32768);
  int*   counts = (int*)(sm2 + 65536);
  float* wgt    = (float*)(ws + (60u << 20));        // 128 KiB

  gating_kernel<<<NT / 4, 256, 0, stream>>>(x, Wg, bg, wgt, tidx, tval, counts);
  cvt_x_kernel<<<(NT * DD / 4 + 255) / 256, 256, 0, stream>>>(x, xb, NT * DD);

  for (int e = 0; e < NEXP; e++) {
    transpose_cvt_kernel<<<dim3(HH / 32, DD / 32, 1), 256, 0, stream>>>(
        W1 + (size_t)e * DD * HH, w1t, DD, HH);
    gemm_bt_kernel<1, false><<<dim3(HH / 128, NT / 128, 1), 256, 0, stream>>>(
        xb, w1t, b1, hb, nullptr, nullptr, nullptr, nullptr, nullptr, HH, DD, e);
    transpose_cvt_kernel<<<dim3(DD / 32, HH / 32, 1), 256, 0, stream>>>(
        W2 + (size_t)e * HH * DD, w2t, HH, DD);
    gemm_bt_kernel<2, false><<<dim3(DD / 128, NT / 128, 1), 256, 0, stream>>>(
        hb, w2t, b2, out, nullptr, nullptr, wgt, nullptr, nullptr, DD, HH, e);
  }
}